// Round 5
// baseline (426.931 us; speedup 1.0000x reference)
//
#include <hip/hip_runtime.h>

#define IMG_H 256
#define IMG_W 256
#define N_IMG 1024 // 16*64

__device__ __forceinline__ float4 fmax4(const float4 a, const float4 b) {
    return make_float4(fmaxf(a.x, b.x), fmaxf(a.y, b.y), fmaxf(a.z, b.z), fmaxf(a.w, b.w));
}

// Fused hex maxpool: out[h][w] = max over 19-tap hex window, OOB -> 0.0
// w even: col w rows h-2..h+2 ; cols w+-1 rows h-2..h+1 ; cols w+-2 rows h-1..h+1
// w odd : col w rows h-2..h+2 ; cols w+-1 rows h-1..h+2 ; cols w+-2 rows h-1..h+1
//
// One wave per output row: 262144 independent waves, 5 unconditional 1 KiB
// loads in flight per wave, no LDS, no barriers. Vertical reuse via L1
// (block = 4 consecutive rows -> 8 KB footprint) + LLC.
__global__ __launch_bounds__(256, 8) void hex_maxpool_kernel(const float* __restrict__ in,
                                                             float* __restrict__ out) {
    const int lane = threadIdx.x & 63;
    const int wave = threadIdx.x >> 6;
    const int gw   = blockIdx.x * 4 + wave;   // 0 .. 262143
    const int img  = gw >> 8;                 // 0 .. 1023
    const int h    = gw & 255;                // 0 .. 255
    const int col  = lane * 4;                // 64 lanes * 4 = full 256-col row

    const float* p = in  + (size_t)img * (IMG_H * IMG_W);
    float*       q = out + (size_t)img * (IMG_H * IMG_W);

    // clamp row addresses so all 5 loads issue unconditionally (max MLP),
    // then wave-uniformly zero the out-of-bounds ones (pad value is 0.0).
    const int hm2 = h - 2, hm1 = h - 1, hp1 = h + 1, hp2 = h + 2;
    float4 w0 = *reinterpret_cast<const float4*>(p + (size_t)(hm2 < 0 ? 0 : hm2) * IMG_W + col);
    float4 w1 = *reinterpret_cast<const float4*>(p + (size_t)(hm1 < 0 ? 0 : hm1) * IMG_W + col);
    float4 w2 = *reinterpret_cast<const float4*>(p + (size_t)h * IMG_W + col);
    float4 w3 = *reinterpret_cast<const float4*>(p + (size_t)(hp1 > 255 ? 255 : hp1) * IMG_W + col);
    float4 w4 = *reinterpret_cast<const float4*>(p + (size_t)(hp2 > 255 ? 255 : hp2) * IMG_W + col);

    const float4 z = make_float4(0.f, 0.f, 0.f, 0.f);
    if (hm2 < 0)   w0 = z;   // wave-uniform selects
    if (hm1 < 0)   w1 = z;
    if (hp1 > 255) w3 = z;
    if (hp2 > 255) w4 = z;

    // per-column vertical aggregates (4 columns per lane)
    const float4 m3 = fmax4(fmax4(w1, w2), w3); // rows h-1..h+1
    const float4 bu = fmax4(m3, w0);            // rows h-2..h+1
    const float4 bd = fmax4(m3, w4);            // rows h-1..h+2
    const float4 a5 = fmax4(bu, w4);            // rows h-2..h+2

    // cross-lane neighbor aggregates
    float Lbuw = __shfl_up(bu.w, 1);
    float Lm3z = __shfl_up(m3.z, 1);
    float Lm3w = __shfl_up(m3.w, 1);
    float Rbdx = __shfl_down(bd.x, 1);
    float Rm3x = __shfl_down(m3.x, 1);
    float Rm3y = __shfl_down(m3.y, 1);
    if (lane == 0)  { Lbuw = 0.f; Lm3z = 0.f; Lm3w = 0.f; }  // cols -1,-2 pad(0)
    if (lane == 63) { Rbdx = 0.f; Rm3x = 0.f; Rm3y = 0.f; }  // cols 256,257 pad(0)

    float4 o;
    o.x = fmaxf(fmaxf(fmaxf(a5.x, Lbuw), bu.y), fmaxf(Lm3z, m3.z)); // even col
    o.y = fmaxf(fmaxf(fmaxf(a5.y, bd.x), bd.z), fmaxf(Lm3w, m3.w)); // odd col
    o.z = fmaxf(fmaxf(fmaxf(a5.z, bu.y), bu.w), fmaxf(m3.x, Rm3x)); // even col
    o.w = fmaxf(fmaxf(fmaxf(a5.w, bd.z), Rbdx), fmaxf(m3.y, Rm3y)); // odd col

    *reinterpret_cast<float4*>(q + (size_t)h * IMG_W + col) = o;
}

extern "C" void kernel_launch(void* const* d_in, const int* in_sizes, int n_in,
                              void* d_out, int out_size, void* d_ws, size_t ws_size,
                              hipStream_t stream) {
    (void)in_sizes; (void)n_in; (void)d_ws; (void)ws_size; (void)out_size;
    const float* in = (const float*)d_in[0];
    float* out = (float*)d_out;
    // 1024 images * 256 rows = 262144 waves = 65536 blocks of 4 waves
    hex_maxpool_kernel<<<N_IMG * IMG_H / 4, 256, 0, stream>>>(in, out);
}